// Round 9
// baseline (83.533 us; speedup 1.0000x reference)
//
#include <hip/hip_runtime.h>

// Inclusive prefix-sum along L of X[B=8][L=4096][D=64][N=16] fp32.
// Single-pass, zero global sync: each block owns one (b, 128-byte dn-slice)
// for ALL of L. Per-thread serial scan (24 rows in regs + 8 in LDS), then a
// block-level Hillis-Steele scan of the 128 thread-aggregates per column.
// One HBM read + one HBM write = 268 MB total.

typedef float f4 __attribute__((ext_vector_type(4)));

constexpr int BB   = 8;
constexpr int LL   = 4096;
constexpr int DN   = 1024;     // D*N floats, contiguous per (b,l)
constexpr int COLS = 8;        // f4 columns per block = 32 floats = 128 B slice
constexpr int NSL  = DN / (COLS * 4);   // 32 slices per batch
constexpr int TPB  = 1024;     // 16 waves
constexpr int G    = TPB / COLS;        // 128 row-groups
constexpr int R    = LL / G;   // 32 rows per thread
constexpr int RREG = 24;       // rows kept in VGPRs (96 regs)
constexpr int RLDS = R - RREG; // 8 rows kept in LDS (128 KB)

__global__ __launch_bounds__(TPB, 4) void scan_col(const float* __restrict__ x,
                                                   float* __restrict__ out) {
    __shared__ f4 pay[RLDS][TPB];   // 128 KB payload spill-over
    __shared__ f4 agg[G][COLS];     // 16 KB thread aggregates

    const int bid = blockIdx.x;            // b*NSL + s
    const int b = bid >> 5, s = bid & (NSL - 1);
    const int t = threadIdx.x;
    const int dn4 = t & (COLS - 1);         // f4 column within slice
    const int g   = t >> 3;                 // row-group [0,128)

    const size_t colbase = (size_t)b * LL * DN + (size_t)s * (COLS * 4);
    const f4* xp = reinterpret_cast<const f4*>(x + colbase) + dn4;
    const int row0 = g * R;

    // Phase A: serial inclusive scan of this thread's 32 rows.
    f4 run = (f4)0.f;
    f4 v[RREG];
    #pragma unroll
    for (int i = 0; i < RREG; ++i) {
        run += xp[(size_t)(row0 + i) * (DN / 4)];
        v[i] = run;
    }
    #pragma unroll
    for (int i = 0; i < RLDS; ++i) {
        run += xp[(size_t)(row0 + RREG + i) * (DN / 4)];
        pay[i][t] = run;
    }

    // Phase B: Hillis-Steele inclusive scan of 128 aggregates per column.
    agg[g][dn4] = run;
    __syncthreads();
    f4 a = run;
    #pragma unroll
    for (int st = 1; st < G; st <<= 1) {
        f4 nb = (f4)0.f;
        if (g >= st) nb = agg[g - st][dn4];
        __syncthreads();
        a += nb;
        agg[g][dn4] = a;
        __syncthreads();
    }
    // Exclusive offset for this thread = inclusive - own aggregate.
    const f4 off = a - run;

    // Phase C: add offset, write out.
    f4* op = reinterpret_cast<f4*>(out + colbase) + dn4;
    #pragma unroll
    for (int i = 0; i < RREG; ++i)
        op[(size_t)(row0 + i) * (DN / 4)] = v[i] + off;
    #pragma unroll
    for (int i = 0; i < RLDS; ++i)
        op[(size_t)(row0 + RREG + i) * (DN / 4)] = pay[i][t] + off;
}

extern "C" void kernel_launch(void* const* d_in, const int* in_sizes, int n_in,
                              void* d_out, int out_size, void* d_ws, size_t ws_size,
                              hipStream_t stream) {
    const float* x = (const float*)d_in[0];
    float* out = (float*)d_out;
    scan_col<<<dim3(BB * NSL), dim3(TPB), 0, stream>>>(x, out);
}